// Round 2
// baseline (1307.473 us; speedup 1.0000x reference)
//
#include <hip/hip_runtime.h>
#include <hip/hip_bf16.h>
#include <math.h>

#define Bc 2
#define Sc 1024
#define Hc 1024
#define NHc 16
#define NKVc 4
#define HDc 64
#define Ec 8
#define TOPKc 2
#define Ic 3584
#define Tc (Bc*Sc)
#define EPSc 1e-5f

typedef __attribute__((ext_vector_type(8))) short bf16x8;
typedef __attribute__((ext_vector_type(4))) float f32x4;

__device__ __forceinline__ unsigned short f2bf(float f) {
    union { float f; unsigned u; } v; v.f = f;
    unsigned r = v.u + 0x7fffu + ((v.u >> 16) & 1u);
    return (unsigned short)(r >> 16);
}

// hardware packed f32->bf16 (RNE)
__device__ __forceinline__ unsigned cvt_pk_bf16(float lo, float hi) {
    unsigned r;
    asm("v_cvt_pk_bf16_f32 %0, %1, %2" : "=v"(r) : "v"(lo), "v"(hi));
    return r;
}

// ---------------- ws layout (bytes) ----------------
// Pre-router path is fp32 (router top-2 selection is discontinuous in hidden;
// bf16 errors flip expert choices -> O(1) output errors). MoE is bf16 MFMA.
static const size_t OFF_XN1  = 0;                          // fp32 T*H (8MB); reused as attn out
static const size_t OFF_QB   = 8*1024*1024;                // fp32 (8MB)
static const size_t OFF_KB   = OFF_QB + 8*1024*1024;       // fp32 (2MB)
static const size_t OFF_VB   = OFF_KB + 2*1024*1024;       // fp32 (2MB)
static const size_t OFF_XN2F = OFF_VB + 2*1024*1024;       // fp32 T*H (8MB)
static const size_t OFF_XN2B = OFF_XN2F + 8*1024*1024;     // bf16 T*H (4MB)
static const size_t OFF_ACT  = OFF_XN2B + 4*1024*1024;     // bf16 4096*3584 (28MB)
static const size_t OFF_ROUTE= OFF_ACT + (size_t)4096*3584*2;

// ---------------- rmsnorm ----------------
__global__ __launch_bounds__(256) void rmsnorm_kernel(const float* __restrict__ x,
        const float* __restrict__ w, float* __restrict__ outf,
        unsigned short* __restrict__ outb) {
    int t = blockIdx.x;
    int tid = threadIdx.x;
    const float* row = x + (size_t)t * Hc;
    float ss = 0.f;
    for (int h = tid; h < Hc; h += 256) { float v = row[h]; ss += v*v; }
    __shared__ float red[256];
    red[tid] = ss; __syncthreads();
    for (int s = 128; s > 0; s >>= 1) { if (tid < s) red[tid] += red[tid+s]; __syncthreads(); }
    float scale = rsqrtf(red[0] / (float)Hc + EPSc);
    for (int h = tid; h < Hc; h += 256) {
        float v = row[h] * scale * w[h];
        outf[(size_t)t*Hc + h] = v;
        if (outb) outb[(size_t)t*Hc + h] = f2bf(v);
    }
}

// ---------------- fused QKV GEMM fp32 (round-1, verified) ----------------
__global__ __launch_bounds__(256) void qkv_gemm(const float* __restrict__ A,
        const float* __restrict__ wq, const float* __restrict__ wk, const float* __restrict__ wv,
        float* __restrict__ qout, float* __restrict__ kout, float* __restrict__ vout) {
    __shared__ float As[64][17];
    __shared__ float Bs[16][65];
    int n0 = blockIdx.x * 64;
    int m0 = blockIdx.y * 64;
    int tid = threadIdx.x;
    int tx = tid & 15, ty = tid >> 4;
    const float* Bp; int ldb, c0;
    if (n0 < 1024)      { Bp = wq; ldb = 1024; c0 = n0; }
    else if (n0 < 1280) { Bp = wk; ldb = 256;  c0 = n0 - 1024; }
    else                { Bp = wv; ldb = 256;  c0 = n0 - 1280; }
    float acc[4][4] = {};
    for (int k0 = 0; k0 < 1024; k0 += 16) {
        #pragma unroll
        for (int i = 0; i < 4; i++) {
            int lin = tid + i*256; int r = lin >> 4, k = lin & 15;
            As[r][k] = A[(size_t)(m0 + r)*Hc + k0 + k];
        }
        #pragma unroll
        for (int i = 0; i < 4; i++) {
            int lin = tid + i*256; int r = lin >> 6, c = lin & 63;
            Bs[r][c] = Bp[(size_t)(k0 + r)*ldb + c0 + c];
        }
        __syncthreads();
        #pragma unroll
        for (int kk = 0; kk < 16; kk++) {
            float a[4], b[4];
            #pragma unroll
            for (int i = 0; i < 4; i++) a[i] = As[ty*4+i][kk];
            #pragma unroll
            for (int j = 0; j < 4; j++) b[j] = Bs[kk][tx*4+j];
            #pragma unroll
            for (int i = 0; i < 4; i++)
                #pragma unroll
                for (int j = 0; j < 4; j++) acc[i][j] += a[i]*b[j];
        }
        __syncthreads();
    }
    #pragma unroll
    for (int i = 0; i < 4; i++) {
        int m = m0 + ty*4 + i;
        #pragma unroll
        for (int j = 0; j < 4; j++) {
            int n = n0 + tx*4 + j;
            float val = acc[i][j];
            if (n < 1024)      qout[(size_t)m*1024 + n] = val;
            else if (n < 1280) kout[(size_t)m*256 + (n-1024)] = val;
            else               vout[(size_t)m*256 + (n-1280)] = val;
        }
    }
}

// ---------------- RoPE ----------------
__global__ __launch_bounds__(256) void rope_kernel(float* __restrict__ q, float* __restrict__ k) {
    int idx = blockIdx.x*256 + threadIdx.x;
    const int total = Tc*(NHc+NKVc)*32;
    if (idx >= total) return;
    int d = idx & 31;
    int rest = idx >> 5;
    int head = rest % (NHc+NKVc);
    int t = rest / (NHc+NKVc);
    int s = t & (Sc-1);
    float inv = exp2f(-(float)d * 0.62286152f);
    float ang = (float)s * inv;
    float c = cosf(ang), sn = sinf(ang);
    float* base;
    if (head < NHc) base = q + (size_t)t*1024 + head*64;
    else            base = k + (size_t)t*256  + (head-NHc)*64;
    float x1 = base[d], x2 = base[d+32];
    base[d]    = x1*c - x2*sn;
    base[d+32] = x2*c + x1*sn;
}

// ---------------- flash attention fp32 (round-1, verified) ----------------
__global__ __launch_bounds__(256) void attn_kernel(const float* __restrict__ q,
        const float* __restrict__ kbuf, const float* __restrict__ vbuf,
        float* __restrict__ attn) {
    __shared__ float Qs[64][65];
    __shared__ float KVs[64][65];
    __shared__ float Ps[64][65];
    __shared__ float m_s[64], l_s[64], al_s[64];
    int q0 = blockIdx.x * 64;
    int h  = blockIdx.y;
    int b  = blockIdx.z;
    int hk = h >> 2;
    int tid = threadIdx.x;
    int tx = tid & 15, ty = tid >> 4;
    #pragma unroll
    for (int i = 0; i < 16; i++) {
        int lin = tid + i*256; int r = lin >> 6, d = lin & 63;
        Qs[r][d] = q[((size_t)(b*Sc + q0 + r))*1024 + h*64 + d];
    }
    if (tid < 64) { m_s[tid] = -INFINITY; l_s[tid] = 0.f; }
    float O[4][4] = {};
    for (int j0 = 0; j0 <= q0; j0 += 64) {
        __syncthreads();
        #pragma unroll
        for (int i = 0; i < 16; i++) {
            int lin = tid + i*256; int r = lin >> 6, d = lin & 63;
            KVs[r][d] = kbuf[((size_t)(b*Sc + j0 + r))*256 + hk*64 + d];
        }
        __syncthreads();
        float sc[4][4] = {};
        for (int d = 0; d < 64; d++) {
            float a[4], bb[4];
            #pragma unroll
            for (int i = 0; i < 4; i++) a[i] = Qs[ty*4+i][d];
            #pragma unroll
            for (int j = 0; j < 4; j++) bb[j] = KVs[tx*4+j][d];
            #pragma unroll
            for (int i = 0; i < 4; i++)
                #pragma unroll
                for (int j = 0; j < 4; j++) sc[i][j] += a[i]*bb[j];
        }
        bool diag = (j0 == q0);
        #pragma unroll
        for (int i = 0; i < 4; i++) {
            int r = ty*4+i;
            #pragma unroll
            for (int j = 0; j < 4; j++) {
                int c = tx*4+j;
                float v = sc[i][j]*0.125f;
                if (diag && c > r) v = -1e30f;
                Ps[r][c] = v;
            }
        }
        __syncthreads();
        if (tid < 64) {
            int r = tid;
            float mx = -1e30f;
            for (int c = 0; c < 64; c++) mx = fmaxf(mx, Ps[r][c]);
            float newm = fmaxf(m_s[r], mx);
            float alpha = expf(m_s[r] - newm);
            float sum = 0.f;
            for (int c = 0; c < 64; c++) { float p = expf(Ps[r][c] - newm); Ps[r][c] = p; sum += p; }
            l_s[r] = l_s[r]*alpha + sum;
            m_s[r] = newm;
            al_s[r] = alpha;
        }
        #pragma unroll
        for (int i = 0; i < 16; i++) {
            int lin = tid + i*256; int r = lin >> 6, d = lin & 63;
            KVs[r][d] = vbuf[((size_t)(b*Sc + j0 + r))*256 + hk*64 + d];
        }
        __syncthreads();
        #pragma unroll
        for (int i = 0; i < 4; i++) {
            float al = al_s[ty*4+i];
            #pragma unroll
            for (int j = 0; j < 4; j++) O[i][j] *= al;
        }
        for (int c = 0; c < 64; c++) {
            float p[4], vv[4];
            #pragma unroll
            for (int i = 0; i < 4; i++) p[i] = Ps[ty*4+i][c];
            #pragma unroll
            for (int j = 0; j < 4; j++) vv[j] = KVs[c][tx*4+j];
            #pragma unroll
            for (int i = 0; i < 4; i++)
                #pragma unroll
                for (int j = 0; j < 4; j++) O[i][j] += p[i]*vv[j];
        }
    }
    #pragma unroll
    for (int i = 0; i < 4; i++) {
        int r = ty*4+i;
        float inv_l = 1.f / l_s[r];
        int m = b*Sc + q0 + r;
        #pragma unroll
        for (int j = 0; j < 4; j++) {
            int d = tx*4+j;
            attn[(size_t)m*1024 + h*64 + d] = O[i][j]*inv_l;
        }
    }
}

// ---------------- WO GEMM + residual fp32 (round-1, verified) ----------------
__global__ __launch_bounds__(256) void wo_gemm(const float* __restrict__ A,
        const float* __restrict__ wo, const float* __restrict__ resid,
        float* __restrict__ out) {
    __shared__ float As[64][17];
    __shared__ float Bs[16][65];
    int n0 = blockIdx.x * 64;
    int m0 = blockIdx.y * 64;
    int tid = threadIdx.x;
    int tx = tid & 15, ty = tid >> 4;
    float acc[4][4] = {};
    for (int k0 = 0; k0 < 1024; k0 += 16) {
        #pragma unroll
        for (int i = 0; i < 4; i++) {
            int lin = tid + i*256; int r = lin >> 4, k = lin & 15;
            As[r][k] = A[(size_t)(m0 + r)*Hc + k0 + k];
        }
        #pragma unroll
        for (int i = 0; i < 4; i++) {
            int lin = tid + i*256; int r = lin >> 6, c = lin & 63;
            Bs[r][c] = wo[(size_t)(k0 + r)*Hc + n0 + c];
        }
        __syncthreads();
        #pragma unroll
        for (int kk = 0; kk < 16; kk++) {
            float a[4], b[4];
            #pragma unroll
            for (int i = 0; i < 4; i++) a[i] = As[ty*4+i][kk];
            #pragma unroll
            for (int j = 0; j < 4; j++) b[j] = Bs[kk][tx*4+j];
            #pragma unroll
            for (int i = 0; i < 4; i++)
                #pragma unroll
                for (int j = 0; j < 4; j++) acc[i][j] += a[i]*b[j];
        }
        __syncthreads();
    }
    #pragma unroll
    for (int i = 0; i < 4; i++) {
        int m = m0 + ty*4 + i;
        #pragma unroll
        for (int j = 0; j < 4; j++) {
            int n = n0 + tx*4 + j;
            out[(size_t)m*Hc + n] = acc[i][j] + resid[(size_t)m*Hc + n];
        }
    }
}

// ---------------- router (fp32) ----------------
__global__ __launch_bounds__(256) void router_kernel(const float* __restrict__ xn2,
        const float* __restrict__ rw, int* __restrict__ counts,
        int* __restrict__ topk_e, float* __restrict__ topk_w) {
    int t = blockIdx.x, tid = threadIdx.x;
    float part[8] = {};
    for (int h = tid; h < 1024; h += 256) {
        float x = xn2[(size_t)t*Hc + h];
        #pragma unroll
        for (int e = 0; e < 8; e++) part[e] += x * rw[h*8 + e];
    }
    __shared__ float red[8][256];
    #pragma unroll
    for (int e = 0; e < 8; e++) red[e][tid] = part[e];
    __syncthreads();
    for (int s = 128; s > 0; s >>= 1) {
        if (tid < s) {
            #pragma unroll
            for (int e = 0; e < 8; e++) red[e][tid] += red[e][tid+s];
        }
        __syncthreads();
    }
    if (tid == 0) {
        float lg[8]; float mx = -1e30f;
        for (int e = 0; e < 8; e++) { lg[e] = red[e][0]; mx = fmaxf(mx, lg[e]); }
        float p[8]; float sum = 0.f;
        for (int e = 0; e < 8; e++) { p[e] = expf(lg[e]-mx); sum += p[e]; }
        for (int e = 0; e < 8; e++) p[e] /= sum;
        int e0 = 0;
        for (int e = 1; e < 8; e++) if (p[e] > p[e0]) e0 = e;
        int e1 = -1;
        for (int e = 0; e < 8; e++) { if (e == e0) continue; if (e1 < 0 || p[e] > p[e1]) e1 = e; }
        float w0 = p[e0], w1 = p[e1]; float wsum = w0 + w1; w0 /= wsum; w1 /= wsum;
        topk_e[t*2] = e0; topk_e[t*2+1] = e1;
        topk_w[t*2] = w0; topk_w[t*2+1] = w1;
        atomicAdd(&counts[e0], 1); atomicAdd(&counts[e1], 1);
    }
}

__global__ void prefix_kernel(const int* __restrict__ counts, int* __restrict__ offsets) {
    if (threadIdx.x == 0 && blockIdx.x == 0) {
        int acc = 0;
        for (int e = 0; e < 8; e++) { offsets[e] = acc; acc += counts[e]; }
    }
}

__global__ __launch_bounds__(256) void fill_kernel(const int* __restrict__ topk_e,
        const float* __restrict__ topk_w, const int* __restrict__ offsets,
        int* __restrict__ fill, int* __restrict__ list_tok, float* __restrict__ list_w) {
    int t = blockIdx.x*256 + threadIdx.x;
    if (t >= Tc) return;
    #pragma unroll
    for (int j = 0; j < 2; j++) {
        int e = topk_e[t*2+j]; float w = topk_w[t*2+j];
        int slot = atomicAdd(&fill[e], 1);
        list_tok[offsets[e]+slot] = t;
        list_w[offsets[e]+slot] = w;
    }
}

// ---------------- gate+up fused bf16 MFMA GEMM v3 ----------------
// BM=128, BN=64, BK=32, 4 waves (2x2). Coalesced vector B loads (lanes fastest
// along n: 16 lanes x 16B = 256B segments) + v_cvt_pk_bf16 + 2-phase register
// prefetch pipeline (issue tile t+1 loads right after barrier so HBM latency
// hides under MFMA of tile t).
__global__ __launch_bounds__(256) void gemm_gateup(const unsigned short* __restrict__ xn2b,
        const float* __restrict__ wg, const float* __restrict__ wu,
        const int* __restrict__ counts, const int* __restrict__ offsets,
        const int* __restrict__ list_tok, unsigned short* __restrict__ act) {
    int e = blockIdx.z;
    int cnt = counts[e];
    int m0 = blockIdx.y * 128;
    if (m0 >= cnt) return;
    int n0 = blockIdx.x * 64;
    int aoff = offsets[e];
    __shared__ unsigned short As[128*40];
    __shared__ unsigned short Bg[64*40];
    __shared__ unsigned short Bu[64*40];
    __shared__ int toks[128];
    int tid = threadIdx.x;
    if (tid < 128) toks[tid] = list_tok[aoff + min(m0 + tid, cnt-1)];
    __syncthreads();
    const float* Bgp = wg + (size_t)e*Hc*Ic + n0;
    const float* Bup = wu + (size_t)e*Hc*Ic + n0;
    int lane = tid & 63, wave = tid >> 6;
    int wm = wave >> 1, wn = wave & 1;
    int ml = lane & 15, quad = lane >> 4;
    int n4 = tid & 15, kp = tid >> 4;   // n fastest across lanes -> coalesced loads
    // A staging slots: r = lin>>2 (4 lanes per row, 64B contiguous)
    int ar0 = tid >> 2, ap0 = tid & 3;
    int ar1 = (tid + 256) >> 2, ap1 = (tid + 256) & 3;

    uint4 pa0, pa1;
    f32x4 pg0, pg1, pu0, pu1;
    #define GU_LOAD(K0) { \
        pa0 = *reinterpret_cast<const uint4*>(xn2b + (size_t)toks[ar0]*Hc + (K0) + ap0*8); \
        pa1 = *reinterpret_cast<const uint4*>(xn2b + (size_t)toks[ar1]*Hc + (K0) + ap1*8); \
        const float* gp = Bgp + (size_t)((K0) + 2*kp)*Ic + n4*4; \
        const float* up = Bup + (size_t)((K0) + 2*kp)*Ic + n4*4; \
        pg0 = *reinterpret_cast<const f32x4*>(gp); \
        pg1 = *reinterpret_cast<const f32x4*>(gp + Ic); \
        pu0 = *reinterpret_cast<const f32x4*>(up); \
        pu1 = *reinterpret_cast<const f32x4*>(up + Ic); \
    }

    f32x4 accg[4][2] = {}, accu[4][2] = {};
    GU_LOAD(0);
    for (int k0 = 0; k0 < Hc; k0 += 32) {
        // store staged regs to LDS
        *reinterpret_cast<uint4*>(&As[ar0*40 + ap0*8]) = pa0;
        *reinterpret_cast<uint4*>(&As[ar1*40 + ap1*8]) = pa1;
        #pragma unroll
        for (int j = 0; j < 4; j++) {
            *reinterpret_cast<unsigned*>(&Bg[(n4*4+j)*40 + 2*kp]) = cvt_pk_bf16(pg0[j], pg1[j]);
            *reinterpret_cast<unsigned*>(&Bu[(n4*4+j)*40 + 2*kp]) = cvt_pk_bf16(pu0[j], pu1[j]);
        }
        __syncthreads();
        if (k0 + 32 < Hc) GU_LOAD(k0 + 32);   // next tile in flight during MFMA
        bf16x8 a[4], bg[2], bu[2];
        #pragma unroll
        for (int mt = 0; mt < 4; mt++)
            a[mt] = *reinterpret_cast<const bf16x8*>(&As[(wm*64 + mt*16 + ml)*40 + quad*8]);
        #pragma unroll
        for (int nt = 0; nt < 2; nt++) {
            bg[nt] = *reinterpret_cast<const bf16x8*>(&Bg[(wn*32 + nt*16 + ml)*40 + quad*8]);
            bu[nt] = *reinterpret_cast<const bf16x8*>(&Bu[(wn*32 + nt*16 + ml)*40 + quad*8]);
        }
        #pragma unroll
        for (int mt = 0; mt < 4; mt++)
            #pragma unroll
            for (int nt = 0; nt < 2; nt++) {
                accg[mt][nt] = __builtin_amdgcn_mfma_f32_16x16x32_bf16(a[mt], bg[nt], accg[mt][nt], 0, 0, 0);
                accu[mt][nt] = __builtin_amdgcn_mfma_f32_16x16x32_bf16(a[mt], bu[nt], accu[mt][nt], 0, 0, 0);
            }
        __syncthreads();
    }
    #undef GU_LOAD
    #pragma unroll
    for (int mt = 0; mt < 4; mt++)
        #pragma unroll
        for (int nt = 0; nt < 2; nt++)
            #pragma unroll
            for (int rg = 0; rg < 4; rg++) {
                int rowl = wm*64 + mt*16 + quad*4 + rg;
                if (m0 + rowl < cnt) {
                    int n = n0 + wn*32 + nt*16 + ml;
                    float g = accg[mt][nt][rg], u = accu[mt][nt][rg];
                    float sg = g / (1.f + expf(-g));
                    act[(size_t)(aoff + m0 + rowl)*Ic + n] = f2bf(sg * u);
                }
            }
}

// ---------------- down bf16 MFMA GEMM v3: BM=64, BN=128 + prefetch pipeline ----
// BM halved for 2x active blocks (latency hiding was the round-1 bottleneck:
// 256 active blocks = 1/CU = 11% occupancy). Coalesced vector B loads.
__global__ __launch_bounds__(256) void gemm_down(const unsigned short* __restrict__ act,
        const float* __restrict__ wd, const int* __restrict__ counts,
        const int* __restrict__ offsets, const int* __restrict__ list_tok,
        const float* __restrict__ list_w, float* __restrict__ out) {
    int e = blockIdx.z;
    int cnt = counts[e];
    int m0 = blockIdx.y * 64;
    if (m0 >= cnt) return;
    int n0 = blockIdx.x * 128;
    int aoff = offsets[e];
    __shared__ unsigned short As[64*40];
    __shared__ unsigned short Bs[128*40];
    const unsigned short* A = act + (size_t)(aoff + m0)*Ic;
    const float* B = wd + (size_t)e*Ic*Hc + n0;
    int rowclamp = cnt - 1 - m0;
    int tid = threadIdx.x;
    int lane = tid & 63, wave = tid >> 6;
    int wm = wave >> 1, wn = wave & 1;
    int ml = lane & 15, quad = lane >> 4;
    // A: 64 rows x 4 parts = 256 slots, 1 per thread
    int ar = tid >> 2, ap = tid & 3;
    int arc = min(ar, rowclamp);
    // B: 32 n4-slots x 16 kp = 512 slots, 2 per thread; n fastest -> coalesced
    int n4a = tid & 31, kpa = tid >> 5;          // slot 0 (kp 0..7)
    int n4b = n4a, kpb = kpa + 8;                // slot 1 (kp 8..15)

    uint4 pa;
    f32x4 pb0a, pb1a, pb0b, pb1b;
    #define DN_LOAD(K0) { \
        pa = *reinterpret_cast<const uint4*>(A + (size_t)arc*Ic + (K0) + ap*8); \
        const float* bpa = B + (size_t)((K0) + 2*kpa)*Hc + n4a*4; \
        const float* bpb = B + (size_t)((K0) + 2*kpb)*Hc + n4b*4; \
        pb0a = *reinterpret_cast<const f32x4*>(bpa); \
        pb1a = *reinterpret_cast<const f32x4*>(bpa + Hc); \
        pb0b = *reinterpret_cast<const f32x4*>(bpb); \
        pb1b = *reinterpret_cast<const f32x4*>(bpb + Hc); \
    }

    f32x4 acc[2][4] = {};
    DN_LOAD(0);
    for (int k0 = 0; k0 < Ic; k0 += 32) {
        *reinterpret_cast<uint4*>(&As[ar*40 + ap*8]) = pa;
        #pragma unroll
        for (int j = 0; j < 4; j++) {
            *reinterpret_cast<unsigned*>(&Bs[(n4a*4+j)*40 + 2*kpa]) = cvt_pk_bf16(pb0a[j], pb1a[j]);
            *reinterpret_cast<unsigned*>(&Bs[(n4b*4+j)*40 + 2*kpb]) = cvt_pk_bf16(pb0b[j], pb1b[j]);
        }
        __syncthreads();
        if (k0 + 32 < Ic) DN_LOAD(k0 + 32);
        bf16x8 a[2], b[4];
        #pragma unroll
        for (int mt = 0; mt < 2; mt++)
            a[mt] = *reinterpret_cast<const bf16x8*>(&As[(wm*32 + mt*16 + ml)*40 + quad*8]);
        #pragma unroll
        for (int nt = 0; nt < 4; nt++)
            b[nt] = *reinterpret_cast<const bf16x8*>(&Bs[(wn*64 + nt*16 + ml)*40 + quad*8]);
        #pragma unroll
        for (int mt = 0; mt < 2; mt++)
            #pragma unroll
            for (int nt = 0; nt < 4; nt++)
                acc[mt][nt] = __builtin_amdgcn_mfma_f32_16x16x32_bf16(a[mt], b[nt], acc[mt][nt], 0, 0, 0);
        __syncthreads();
    }
    #undef DN_LOAD
    #pragma unroll
    for (int mt = 0; mt < 2; mt++)
        #pragma unroll
        for (int nt = 0; nt < 4; nt++)
            #pragma unroll
            for (int rg = 0; rg < 4; rg++) {
                int rowl = wm*32 + mt*16 + quad*4 + rg;
                if (m0 + rowl < cnt) {
                    int t = list_tok[aoff + m0 + rowl];
                    float w = list_w[aoff + m0 + rowl];
                    int n = n0 + wn*64 + nt*16 + ml;
                    atomicAdd(&out[(size_t)t*Hc + n], w * acc[mt][nt][rg]);
                }
            }
}

// ---------------- launch ----------------
extern "C" void kernel_launch(void* const* d_in, const int* in_sizes, int n_in,
                              void* d_out, int out_size, void* d_ws, size_t ws_size,
                              hipStream_t stream) {
    const float* hidden = (const float*)d_in[0];
    const float* ln1 = (const float*)d_in[2];
    const float* ln2 = (const float*)d_in[3];
    const float* wq  = (const float*)d_in[4];
    const float* wk  = (const float*)d_in[5];
    const float* wv  = (const float*)d_in[6];
    const float* wo  = (const float*)d_in[7];
    const float* rw  = (const float*)d_in[8];
    const float* wg  = (const float*)d_in[9];
    const float* wu  = (const float*)d_in[10];
    const float* wd  = (const float*)d_in[11];
    float* out = (float*)d_out;
    char* ws = (char*)d_ws;

    float* xn1f  = (float*)(ws + OFF_XN1);
    float* attnf = xn1f;   // reuse after qkv
    float* qb    = (float*)(ws + OFF_QB);
    float* kb    = (float*)(ws + OFF_KB);
    float* vb    = (float*)(ws + OFF_VB);
    float* xn2f  = (float*)(ws + OFF_XN2F);
    unsigned short* xn2b = (unsigned short*)(ws + OFF_XN2B);
    unsigned short* act  = (unsigned short*)(ws + OFF_ACT);
    int*   route    = (int*)(ws + OFF_ROUTE);
    int*   counts   = route;
    int*   fillc    = route + 8;
    int*   offsets  = route + 16;
    int*   topk_e   = route + 24;
    float* topk_w   = (float*)(route + 24 + 2*Tc);
    int*   list_tok = route + 24 + 4*Tc;
    float* list_w   = (float*)(route + 24 + 6*Tc);

    hipMemsetAsync(counts, 0, 16*sizeof(int), stream);

    rmsnorm_kernel<<<Tc, 256, 0, stream>>>(hidden, ln1, xn1f, nullptr);
    qkv_gemm<<<dim3(24, 32), 256, 0, stream>>>(xn1f, wq, wk, wv, qb, kb, vb);
    rope_kernel<<<(Tc*(NHc+NKVc)*32 + 255)/256, 256, 0, stream>>>(qb, kb);
    attn_kernel<<<dim3(16, 16, 2), 256, 0, stream>>>(qb, kb, vb, attnf);
    wo_gemm<<<dim3(16, 32), 256, 0, stream>>>(attnf, wo, hidden, out);
    rmsnorm_kernel<<<Tc, 256, 0, stream>>>(out, ln2, xn2f, xn2b);
    router_kernel<<<Tc, 256, 0, stream>>>(xn2f, rw, counts, topk_e, topk_w);
    prefix_kernel<<<1, 64, 0, stream>>>(counts, offsets);
    fill_kernel<<<(Tc+255)/256, 256, 0, stream>>>(topk_e, topk_w, offsets, fillc, list_tok, list_w);
    gemm_gateup<<<dim3(56, 16, 8), 256, 0, stream>>>(xn2b, wg, wu, counts, offsets, list_tok, act);
    gemm_down<<<dim3(8, 32, 8), 256, 0, stream>>>(act, wd, counts, offsets, list_tok, list_w, out);
}

// Round 4
// 1154.099 us; speedup vs baseline: 1.1329x; 1.1329x over previous
//
#include <hip/hip_runtime.h>
#include <hip/hip_bf16.h>
#include <math.h>

#define Bc 2
#define Sc 1024
#define Hc 1024
#define NHc 16
#define NKVc 4
#define HDc 64
#define Ec 8
#define TOPKc 2
#define Ic 3584
#define Tc (Bc*Sc)
#define EPSc 1e-5f

typedef __attribute__((ext_vector_type(8))) short bf16x8;
typedef __attribute__((ext_vector_type(4))) float f32x4;

__device__ __forceinline__ unsigned short f2bf(float f) {
    union { float f; unsigned u; } v; v.f = f;
    unsigned r = v.u + 0x7fffu + ((v.u >> 16) & 1u);
    return (unsigned short)(r >> 16);
}

// hardware packed f32->bf16 (RNE)
__device__ __forceinline__ unsigned cvt_pk_bf16(float lo, float hi) {
    unsigned r;
    asm("v_cvt_pk_bf16_f32 %0, %1, %2" : "=v"(r) : "v"(lo), "v"(hi));
    return r;
}

// async global->LDS, 16B per lane. LDS dest = wave-uniform base + lane*16.
#define GLL(g, l) __builtin_amdgcn_global_load_lds( \
    (const __attribute__((address_space(1))) void*)(g), \
    (__attribute__((address_space(3))) void*)(l), 16, 0, 0)

// ---------------- ws layout (bytes) ----------------
// Pre-router path is fp32 (router top-2 selection is discontinuous in hidden;
// bf16 errors flip expert choices -> O(1) output errors). MoE is bf16 MFMA.
static const size_t OFF_XN1  = 0;                          // fp32 T*H (8MB); reused as attn out
static const size_t OFF_QB   = 8*1024*1024;                // fp32 (8MB)
static const size_t OFF_KB   = OFF_QB + 8*1024*1024;       // fp32 (2MB)
static const size_t OFF_VB   = OFF_KB + 2*1024*1024;       // fp32 (2MB)
static const size_t OFF_XN2F = OFF_VB + 2*1024*1024;       // fp32 T*H (8MB)
static const size_t OFF_XN2B = OFF_XN2F + 8*1024*1024;     // bf16 T*H (4MB)
static const size_t OFF_ACT  = OFF_XN2B + 4*1024*1024;     // bf16 4096*3584 (28MB)
static const size_t OFF_ROUTE= OFF_ACT + (size_t)4096*3584*2;

// ---------------- rmsnorm ----------------
__global__ __launch_bounds__(256) void rmsnorm_kernel(const float* __restrict__ x,
        const float* __restrict__ w, float* __restrict__ outf,
        unsigned short* __restrict__ outb) {
    int t = blockIdx.x;
    int tid = threadIdx.x;
    const float* row = x + (size_t)t * Hc;
    float ss = 0.f;
    for (int h = tid; h < Hc; h += 256) { float v = row[h]; ss += v*v; }
    __shared__ float red[256];
    red[tid] = ss; __syncthreads();
    for (int s = 128; s > 0; s >>= 1) { if (tid < s) red[tid] += red[tid+s]; __syncthreads(); }
    float scale = rsqrtf(red[0] / (float)Hc + EPSc);
    for (int h = tid; h < Hc; h += 256) {
        float v = row[h] * scale * w[h];
        outf[(size_t)t*Hc + h] = v;
        if (outb) outb[(size_t)t*Hc + h] = f2bf(v);
    }
}

// ---------------- fused QKV GEMM fp32 (round-1, verified) ----------------
__global__ __launch_bounds__(256) void qkv_gemm(const float* __restrict__ A,
        const float* __restrict__ wq, const float* __restrict__ wk, const float* __restrict__ wv,
        float* __restrict__ qout, float* __restrict__ kout, float* __restrict__ vout) {
    __shared__ float As[64][17];
    __shared__ float Bs[16][65];
    int n0 = blockIdx.x * 64;
    int m0 = blockIdx.y * 64;
    int tid = threadIdx.x;
    int tx = tid & 15, ty = tid >> 4;
    const float* Bp; int ldb, c0;
    if (n0 < 1024)      { Bp = wq; ldb = 1024; c0 = n0; }
    else if (n0 < 1280) { Bp = wk; ldb = 256;  c0 = n0 - 1024; }
    else                { Bp = wv; ldb = 256;  c0 = n0 - 1280; }
    float acc[4][4] = {};
    for (int k0 = 0; k0 < 1024; k0 += 16) {
        #pragma unroll
        for (int i = 0; i < 4; i++) {
            int lin = tid + i*256; int r = lin >> 4, k = lin & 15;
            As[r][k] = A[(size_t)(m0 + r)*Hc + k0 + k];
        }
        #pragma unroll
        for (int i = 0; i < 4; i++) {
            int lin = tid + i*256; int r = lin >> 6, c = lin & 63;
            Bs[r][c] = Bp[(size_t)(k0 + r)*ldb + c0 + c];
        }
        __syncthreads();
        #pragma unroll
        for (int kk = 0; kk < 16; kk++) {
            float a[4], b[4];
            #pragma unroll
            for (int i = 0; i < 4; i++) a[i] = As[ty*4+i][kk];
            #pragma unroll
            for (int j = 0; j < 4; j++) b[j] = Bs[kk][tx*4+j];
            #pragma unroll
            for (int i = 0; i < 4; i++)
                #pragma unroll
                for (int j = 0; j < 4; j++) acc[i][j] += a[i]*b[j];
        }
        __syncthreads();
    }
    #pragma unroll
    for (int i = 0; i < 4; i++) {
        int m = m0 + ty*4 + i;
        #pragma unroll
        for (int j = 0; j < 4; j++) {
            int n = n0 + tx*4 + j;
            float val = acc[i][j];
            if (n < 1024)      qout[(size_t)m*1024 + n] = val;
            else if (n < 1280) kout[(size_t)m*256 + (n-1024)] = val;
            else               vout[(size_t)m*256 + (n-1280)] = val;
        }
    }
}

// ---------------- RoPE ----------------
__global__ __launch_bounds__(256) void rope_kernel(float* __restrict__ q, float* __restrict__ k) {
    int idx = blockIdx.x*256 + threadIdx.x;
    const int total = Tc*(NHc+NKVc)*32;
    if (idx >= total) return;
    int d = idx & 31;
    int rest = idx >> 5;
    int head = rest % (NHc+NKVc);
    int t = rest / (NHc+NKVc);
    int s = t & (Sc-1);
    float inv = exp2f(-(float)d * 0.62286152f);
    float ang = (float)s * inv;
    float c = cosf(ang), sn = sinf(ang);
    float* base;
    if (head < NHc) base = q + (size_t)t*1024 + head*64;
    else            base = k + (size_t)t*256  + (head-NHc)*64;
    float x1 = base[d], x2 = base[d+32];
    base[d]    = x1*c - x2*sn;
    base[d+32] = x2*c + x1*sn;
}

// ---------------- flash attention fp32 (round-1, verified) ----------------
__global__ __launch_bounds__(256) void attn_kernel(const float* __restrict__ q,
        const float* __restrict__ kbuf, const float* __restrict__ vbuf,
        float* __restrict__ attn) {
    __shared__ float Qs[64][65];
    __shared__ float KVs[64][65];
    __shared__ float Ps[64][65];
    __shared__ float m_s[64], l_s[64], al_s[64];
    int q0 = blockIdx.x * 64;
    int h  = blockIdx.y;
    int b  = blockIdx.z;
    int hk = h >> 2;
    int tid = threadIdx.x;
    int tx = tid & 15, ty = tid >> 4;
    #pragma unroll
    for (int i = 0; i < 16; i++) {
        int lin = tid + i*256; int r = lin >> 6, d = lin & 63;
        Qs[r][d] = q[((size_t)(b*Sc + q0 + r))*1024 + h*64 + d];
    }
    if (tid < 64) { m_s[tid] = -INFINITY; l_s[tid] = 0.f; }
    float O[4][4] = {};
    for (int j0 = 0; j0 <= q0; j0 += 64) {
        __syncthreads();
        #pragma unroll
        for (int i = 0; i < 16; i++) {
            int lin = tid + i*256; int r = lin >> 6, d = lin & 63;
            KVs[r][d] = kbuf[((size_t)(b*Sc + j0 + r))*256 + hk*64 + d];
        }
        __syncthreads();
        float sc[4][4] = {};
        for (int d = 0; d < 64; d++) {
            float a[4], bb[4];
            #pragma unroll
            for (int i = 0; i < 4; i++) a[i] = Qs[ty*4+i][d];
            #pragma unroll
            for (int j = 0; j < 4; j++) bb[j] = KVs[tx*4+j][d];
            #pragma unroll
            for (int i = 0; i < 4; i++)
                #pragma unroll
                for (int j = 0; j < 4; j++) sc[i][j] += a[i]*bb[j];
        }
        bool diag = (j0 == q0);
        #pragma unroll
        for (int i = 0; i < 4; i++) {
            int r = ty*4+i;
            #pragma unroll
            for (int j = 0; j < 4; j++) {
                int c = tx*4+j;
                float v = sc[i][j]*0.125f;
                if (diag && c > r) v = -1e30f;
                Ps[r][c] = v;
            }
        }
        __syncthreads();
        if (tid < 64) {
            int r = tid;
            float mx = -1e30f;
            for (int c = 0; c < 64; c++) mx = fmaxf(mx, Ps[r][c]);
            float newm = fmaxf(m_s[r], mx);
            float alpha = expf(m_s[r] - newm);
            float sum = 0.f;
            for (int c = 0; c < 64; c++) { float p = expf(Ps[r][c] - newm); Ps[r][c] = p; sum += p; }
            l_s[r] = l_s[r]*alpha + sum;
            m_s[r] = newm;
            al_s[r] = alpha;
        }
        #pragma unroll
        for (int i = 0; i < 16; i++) {
            int lin = tid + i*256; int r = lin >> 6, d = lin & 63;
            KVs[r][d] = vbuf[((size_t)(b*Sc + j0 + r))*256 + hk*64 + d];
        }
        __syncthreads();
        #pragma unroll
        for (int i = 0; i < 4; i++) {
            float al = al_s[ty*4+i];
            #pragma unroll
            for (int j = 0; j < 4; j++) O[i][j] *= al;
        }
        for (int c = 0; c < 64; c++) {
            float p[4], vv[4];
            #pragma unroll
            for (int i = 0; i < 4; i++) p[i] = Ps[ty*4+i][c];
            #pragma unroll
            for (int j = 0; j < 4; j++) vv[j] = KVs[c][tx*4+j];
            #pragma unroll
            for (int i = 0; i < 4; i++)
                #pragma unroll
                for (int j = 0; j < 4; j++) O[i][j] += p[i]*vv[j];
        }
    }
    #pragma unroll
    for (int i = 0; i < 4; i++) {
        int r = ty*4+i;
        float inv_l = 1.f / l_s[r];
        int m = b*Sc + q0 + r;
        #pragma unroll
        for (int j = 0; j < 4; j++) {
            int d = tx*4+j;
            attn[(size_t)m*1024 + h*64 + d] = O[i][j]*inv_l;
        }
    }
}

// ---------------- WO GEMM + residual fp32 (round-1, verified) ----------------
__global__ __launch_bounds__(256) void wo_gemm(const float* __restrict__ A,
        const float* __restrict__ wo, const float* __restrict__ resid,
        float* __restrict__ out) {
    __shared__ float As[64][17];
    __shared__ float Bs[16][65];
    int n0 = blockIdx.x * 64;
    int m0 = blockIdx.y * 64;
    int tid = threadIdx.x;
    int tx = tid & 15, ty = tid >> 4;
    float acc[4][4] = {};
    for (int k0 = 0; k0 < 1024; k0 += 16) {
        #pragma unroll
        for (int i = 0; i < 4; i++) {
            int lin = tid + i*256; int r = lin >> 4, k = lin & 15;
            As[r][k] = A[(size_t)(m0 + r)*Hc + k0 + k];
        }
        #pragma unroll
        for (int i = 0; i < 4; i++) {
            int lin = tid + i*256; int r = lin >> 6, c = lin & 63;
            Bs[r][c] = wo[(size_t)(k0 + r)*Hc + n0 + c];
        }
        __syncthreads();
        #pragma unroll
        for (int kk = 0; kk < 16; kk++) {
            float a[4], b[4];
            #pragma unroll
            for (int i = 0; i < 4; i++) a[i] = As[ty*4+i][kk];
            #pragma unroll
            for (int j = 0; j < 4; j++) b[j] = Bs[kk][tx*4+j];
            #pragma unroll
            for (int i = 0; i < 4; i++)
                #pragma unroll
                for (int j = 0; j < 4; j++) acc[i][j] += a[i]*b[j];
        }
        __syncthreads();
    }
    #pragma unroll
    for (int i = 0; i < 4; i++) {
        int m = m0 + ty*4 + i;
        #pragma unroll
        for (int j = 0; j < 4; j++) {
            int n = n0 + tx*4 + j;
            out[(size_t)m*Hc + n] = acc[i][j] + resid[(size_t)m*Hc + n];
        }
    }
}

// ---------------- router (fp32) ----------------
__global__ __launch_bounds__(256) void router_kernel(const float* __restrict__ xn2,
        const float* __restrict__ rw, int* __restrict__ counts,
        int* __restrict__ topk_e, float* __restrict__ topk_w) {
    int t = blockIdx.x, tid = threadIdx.x;
    float part[8] = {};
    for (int h = tid; h < 1024; h += 256) {
        float x = xn2[(size_t)t*Hc + h];
        #pragma unroll
        for (int e = 0; e < 8; e++) part[e] += x * rw[h*8 + e];
    }
    __shared__ float red[8][256];
    #pragma unroll
    for (int e = 0; e < 8; e++) red[e][tid] = part[e];
    __syncthreads();
    for (int s = 128; s > 0; s >>= 1) {
        if (tid < s) {
            #pragma unroll
            for (int e = 0; e < 8; e++) red[e][tid] += red[e][tid+s];
        }
        __syncthreads();
    }
    if (tid == 0) {
        float lg[8]; float mx = -1e30f;
        for (int e = 0; e < 8; e++) { lg[e] = red[e][0]; mx = fmaxf(mx, lg[e]); }
        float p[8]; float sum = 0.f;
        for (int e = 0; e < 8; e++) { p[e] = expf(lg[e]-mx); sum += p[e]; }
        for (int e = 0; e < 8; e++) p[e] /= sum;
        int e0 = 0;
        for (int e = 1; e < 8; e++) if (p[e] > p[e0]) e0 = e;
        int e1 = -1;
        for (int e = 0; e < 8; e++) { if (e == e0) continue; if (e1 < 0 || p[e] > p[e1]) e1 = e; }
        float w0 = p[e0], w1 = p[e1]; float wsum = w0 + w1; w0 /= wsum; w1 /= wsum;
        topk_e[t*2] = e0; topk_e[t*2+1] = e1;
        topk_w[t*2] = w0; topk_w[t*2+1] = w1;
        atomicAdd(&counts[e0], 1); atomicAdd(&counts[e1], 1);
    }
}

__global__ void prefix_kernel(const int* __restrict__ counts, int* __restrict__ offsets) {
    if (threadIdx.x == 0 && blockIdx.x == 0) {
        int acc = 0;
        for (int e = 0; e < 8; e++) { offsets[e] = acc; acc += counts[e]; }
    }
}

__global__ __launch_bounds__(256) void fill_kernel(const int* __restrict__ topk_e,
        const float* __restrict__ topk_w, const int* __restrict__ offsets,
        int* __restrict__ fill, int* __restrict__ list_tok, float* __restrict__ list_w) {
    int t = blockIdx.x*256 + threadIdx.x;
    if (t >= Tc) return;
    #pragma unroll
    for (int j = 0; j < 2; j++) {
        int e = topk_e[t*2+j]; float w = topk_w[t*2+j];
        int slot = atomicAdd(&fill[e], 1);
        list_tok[offsets[e]+slot] = t;
        list_w[offsets[e]+slot] = w;
    }
}

// ---------------- gate+up fused bf16 MFMA GEMM v4 ----------------
// BM=128, BN=64, BK=32, 4 waves (2x2). ALL staging via global_load_lds (16B,
// linear dest; LDS arrays alignas(16)):
// - A (bf16): linear [128 rows][32 k]. Frag ds_read_b128: row stride 64B ->
//   bank group = 4*(ml&1)+quad covers all 8 groups x 8 lanes = balanced.
// - B (fp32): k-major [32 k][64 n]; frag built on read with 8x ds_read_b32
//   (16 consecutive banks, 4-way across quads ~1.58x) + 4x v_cvt_pk_bf16_f32.
// 2-phase pipeline: STAGE(next buf) -> ds_read+MFMA(cur) -> vmcnt(0)+barrier.
__global__ __launch_bounds__(256) void gemm_gateup(const unsigned short* __restrict__ xn2b,
        const float* __restrict__ wg, const float* __restrict__ wu,
        const int* __restrict__ counts, const int* __restrict__ offsets,
        const int* __restrict__ list_tok, unsigned short* __restrict__ act) {
    int e = blockIdx.z;
    int cnt = counts[e];
    int m0 = blockIdx.y * 128;
    if (m0 >= cnt) return;
    int n0 = blockIdx.x * 64;
    int aoff = offsets[e];
    __shared__ alignas(16) unsigned short As[2][128*32];
    __shared__ alignas(16) float Bgs[2][32*64];
    __shared__ alignas(16) float Bus[2][32*64];
    __shared__ int toks[128];
    int tid = threadIdx.x;
    if (tid < 128) toks[tid] = list_tok[aoff + min(m0 + tid, cnt-1)];
    __syncthreads();
    const float* Bgp = wg + (size_t)e*Hc*Ic + n0;
    const float* Bup = wu + (size_t)e*Hc*Ic + n0;
    int lane = tid & 63, wave = tid >> 6;
    int wm = wave >> 1, wn = wave & 1;
    int ml = lane & 15, quad = lane >> 4;
    int wb = wave * 64;   // wave-uniform slot base

    // A staging: slot lin = R*4 + part  (linear)
    const unsigned short* aS0 = xn2b + (size_t)toks[tid>>2]*Hc + (tid&3)*8;
    const unsigned short* aS1 = xn2b + (size_t)toks[(tid+256)>>2]*Hc + (tid&3)*8;
    // B staging: slot lin -> k=lin>>4, np=lin&15 (4 fp32); coalesced 256B/k-row
    const float* gS0 = Bgp + (size_t)(tid>>4)*Ic + (tid&15)*4;
    const float* gS1 = Bgp + (size_t)((tid>>4)+16)*Ic + (tid&15)*4;
    const float* uS0 = Bup + (size_t)(tid>>4)*Ic + (tid&15)*4;
    const float* uS1 = Bup + (size_t)((tid>>4)+16)*Ic + (tid&15)*4;

    #define GU_STAGE(buf, K0) do { \
        GLL(aS0 + (K0), &As[buf][wb*8]); \
        GLL(aS1 + (K0), &As[buf][(256+wb)*8]); \
        GLL(gS0 + (size_t)(K0)*Ic, &Bgs[buf][wb*4]); \
        GLL(gS1 + (size_t)(K0)*Ic, &Bgs[buf][(256+wb)*4]); \
        GLL(uS0 + (size_t)(K0)*Ic, &Bus[buf][wb*4]); \
        GLL(uS1 + (size_t)(K0)*Ic, &Bus[buf][(256+wb)*4]); \
    } while(0)

    f32x4 accg[4][2] = {}, accu[4][2] = {};
    GU_STAGE(0, 0);
    asm volatile("s_waitcnt vmcnt(0)" ::: "memory");
    __syncthreads();
    int cur = 0;
    for (int ks = 0; ks < Hc/32; ks++) {
        if (ks + 1 < Hc/32) GU_STAGE(cur^1, (ks+1)*32);
        bf16x8 a[4];
        #pragma unroll
        for (int mt = 0; mt < 4; mt++) {
            int R = wm*64 + mt*16 + ml;
            a[mt] = *reinterpret_cast<const bf16x8*>(&As[cur][R*32 + quad*8]);
        }
        bf16x8 bg[2], bu[2];
        #pragma unroll
        for (int nt = 0; nt < 2; nt++) {
            int n = wn*32 + nt*16 + ml;
            const float* pg = &Bgs[cur][quad*512 + n];
            const float* pu = &Bus[cur][quad*512 + n];
            union { bf16x8 v; unsigned u[4]; } tg, tu;
            #pragma unroll
            for (int j = 0; j < 4; j++) {
                tg.u[j] = cvt_pk_bf16(pg[(2*j)*64], pg[(2*j+1)*64]);
                tu.u[j] = cvt_pk_bf16(pu[(2*j)*64], pu[(2*j+1)*64]);
            }
            bg[nt] = tg.v; bu[nt] = tu.v;
        }
        #pragma unroll
        for (int mt = 0; mt < 4; mt++)
            #pragma unroll
            for (int nt = 0; nt < 2; nt++) {
                accg[mt][nt] = __builtin_amdgcn_mfma_f32_16x16x32_bf16(a[mt], bg[nt], accg[mt][nt], 0, 0, 0);
                accu[mt][nt] = __builtin_amdgcn_mfma_f32_16x16x32_bf16(a[mt], bu[nt], accu[mt][nt], 0, 0, 0);
            }
        asm volatile("s_waitcnt vmcnt(0)" ::: "memory");
        __syncthreads();
        cur ^= 1;
    }
    #undef GU_STAGE
    #pragma unroll
    for (int mt = 0; mt < 4; mt++)
        #pragma unroll
        for (int nt = 0; nt < 2; nt++)
            #pragma unroll
            for (int rg = 0; rg < 4; rg++) {
                int rowl = wm*64 + mt*16 + quad*4 + rg;
                if (m0 + rowl < cnt) {
                    int n = n0 + wn*32 + nt*16 + ml;
                    float g = accg[mt][nt][rg], u = accu[mt][nt][rg];
                    float sg = g / (1.f + expf(-g));
                    act[(size_t)(aoff + m0 + rowl)*Ic + n] = f2bf(sg * u);
                }
            }
}

// ---------------- down bf16 MFMA GEMM v4: BM=128, BN=64, same structure ----
__global__ __launch_bounds__(256) void gemm_down(const unsigned short* __restrict__ act,
        const float* __restrict__ wd, const int* __restrict__ counts,
        const int* __restrict__ offsets, const int* __restrict__ list_tok,
        const float* __restrict__ list_w, float* __restrict__ out) {
    int e = blockIdx.z;
    int cnt = counts[e];
    int m0 = blockIdx.y * 128;
    if (m0 >= cnt) return;
    int n0 = blockIdx.x * 64;
    int aoff = offsets[e];
    __shared__ alignas(16) unsigned short As[2][128*32];
    __shared__ alignas(16) float Bs[2][32*64];
    const unsigned short* Aexp = act + (size_t)(aoff + m0)*Ic;
    const float* Bp = wd + (size_t)e*Ic*Hc + n0;
    int rowclamp = cnt - 1 - m0;
    int tid = threadIdx.x;
    int lane = tid & 63, wave = tid >> 6;
    int wm = wave >> 1, wn = wave & 1;
    int ml = lane & 15, quad = lane >> 4;
    int wb = wave * 64;

    int R0 = min(tid >> 2, rowclamp);
    int R1 = min((tid + 256) >> 2, rowclamp);
    const unsigned short* aS0 = Aexp + (size_t)R0*Ic + (tid&3)*8;
    const unsigned short* aS1 = Aexp + (size_t)R1*Ic + (tid&3)*8;
    const float* bS0 = Bp + (size_t)(tid>>4)*Hc + (tid&15)*4;
    const float* bS1 = Bp + (size_t)((tid>>4)+16)*Hc + (tid&15)*4;

    #define DN_STAGE(buf, K0) do { \
        GLL(aS0 + (K0), &As[buf][wb*8]); \
        GLL(aS1 + (K0), &As[buf][(256+wb)*8]); \
        GLL(bS0 + (size_t)(K0)*Hc, &Bs[buf][wb*4]); \
        GLL(bS1 + (size_t)(K0)*Hc, &Bs[buf][(256+wb)*4]); \
    } while(0)

    f32x4 acc[4][2] = {};
    DN_STAGE(0, 0);
    asm volatile("s_waitcnt vmcnt(0)" ::: "memory");
    __syncthreads();
    int cur = 0;
    for (int ks = 0; ks < Ic/32; ks++) {
        if (ks + 1 < Ic/32) DN_STAGE(cur^1, (ks+1)*32);
        bf16x8 a[4];
        #pragma unroll
        for (int mt = 0; mt < 4; mt++) {
            int R = wm*64 + mt*16 + ml;
            a[mt] = *reinterpret_cast<const bf16x8*>(&As[cur][R*32 + quad*8]);
        }
        bf16x8 b[2];
        #pragma unroll
        for (int nt = 0; nt < 2; nt++) {
            int n = wn*32 + nt*16 + ml;
            const float* pb = &Bs[cur][quad*512 + n];
            union { bf16x8 v; unsigned u[4]; } tb;
            #pragma unroll
            for (int j = 0; j < 4; j++)
                tb.u[j] = cvt_pk_bf16(pb[(2*j)*64], pb[(2*j+1)*64]);
            b[nt] = tb.v;
        }
        #pragma unroll
        for (int mt = 0; mt < 4; mt++)
            #pragma unroll
            for (int nt = 0; nt < 2; nt++)
                acc[mt][nt] = __builtin_amdgcn_mfma_f32_16x16x32_bf16(a[mt], b[nt], acc[mt][nt], 0, 0, 0);
        asm volatile("s_waitcnt vmcnt(0)" ::: "memory");
        __syncthreads();
        cur ^= 1;
    }
    #undef DN_STAGE
    #pragma unroll
    for (int mt = 0; mt < 4; mt++)
        #pragma unroll
        for (int nt = 0; nt < 2; nt++)
            #pragma unroll
            for (int rg = 0; rg < 4; rg++) {
                int rowl = wm*64 + mt*16 + quad*4 + rg;
                if (m0 + rowl < cnt) {
                    int t = list_tok[aoff + m0 + rowl];
                    float w = list_w[aoff + m0 + rowl];
                    int n = n0 + wn*32 + nt*16 + ml;
                    atomicAdd(&out[(size_t)t*Hc + n], w * acc[mt][nt][rg]);
                }
            }
}

// ---------------- launch ----------------
extern "C" void kernel_launch(void* const* d_in, const int* in_sizes, int n_in,
                              void* d_out, int out_size, void* d_ws, size_t ws_size,
                              hipStream_t stream) {
    const float* hidden = (const float*)d_in[0];
    const float* ln1 = (const float*)d_in[2];
    const float* ln2 = (const float*)d_in[3];
    const float* wq  = (const float*)d_in[4];
    const float* wk  = (const float*)d_in[5];
    const float* wv  = (const float*)d_in[6];
    const float* wo  = (const float*)d_in[7];
    const float* rw  = (const float*)d_in[8];
    const float* wg  = (const float*)d_in[9];
    const float* wu  = (const float*)d_in[10];
    const float* wd  = (const float*)d_in[11];
    float* out = (float*)d_out;
    char* ws = (char*)d_ws;

    float* xn1f  = (float*)(ws + OFF_XN1);
    float* attnf = xn1f;   // reuse after qkv
    float* qb    = (float*)(ws + OFF_QB);
    float* kb    = (float*)(ws + OFF_KB);
    float* vb    = (float*)(ws + OFF_VB);
    float* xn2f  = (float*)(ws + OFF_XN2F);
    unsigned short* xn2b = (unsigned short*)(ws + OFF_XN2B);
    unsigned short* act  = (unsigned short*)(ws + OFF_ACT);
    int*   route    = (int*)(ws + OFF_ROUTE);
    int*   counts   = route;
    int*   fillc    = route + 8;
    int*   offsets  = route + 16;
    int*   topk_e   = route + 24;
    float* topk_w   = (float*)(route + 24 + 2*Tc);
    int*   list_tok = route + 24 + 4*Tc;
    float* list_w   = (float*)(route + 24 + 6*Tc);

    hipMemsetAsync(counts, 0, 16*sizeof(int), stream);

    rmsnorm_kernel<<<Tc, 256, 0, stream>>>(hidden, ln1, xn1f, nullptr);
    qkv_gemm<<<dim3(24, 32), 256, 0, stream>>>(xn1f, wq, wk, wv, qb, kb, vb);
    rope_kernel<<<(Tc*(NHc+NKVc)*32 + 255)/256, 256, 0, stream>>>(qb, kb);
    attn_kernel<<<dim3(16, 16, 2), 256, 0, stream>>>(qb, kb, vb, attnf);
    wo_gemm<<<dim3(16, 32), 256, 0, stream>>>(attnf, wo, hidden, out);
    rmsnorm_kernel<<<Tc, 256, 0, stream>>>(out, ln2, xn2f, xn2b);
    router_kernel<<<Tc, 256, 0, stream>>>(xn2f, rw, counts, topk_e, topk_w);
    prefix_kernel<<<1, 64, 0, stream>>>(counts, offsets);
    fill_kernel<<<(Tc+255)/256, 256, 0, stream>>>(topk_e, topk_w, offsets, fillc, list_tok, list_w);
    gemm_gateup<<<dim3(56, 16, 8), 256, 0, stream>>>(xn2b, wg, wu, counts, offsets, list_tok, act);
    gemm_down<<<dim3(16, 16, 8), 256, 0, stream>>>(act, wd, counts, offsets, list_tok, list_w, out);
}